// Round 2
// baseline (458.791 us; speedup 1.0000x reference)
//
#include <hip/hip_runtime.h>

#define DIMQ 1024
#define NH 4
#define HD 256
#define BSZ 4
#define LQ 2048
#define LKV 2048

typedef __attribute__((ext_vector_type(8))) short bf16x8;
typedef __attribute__((ext_vector_type(4))) float f32x4;

__device__ inline unsigned short f32_to_bf16(float f) {
  union { float f; unsigned u; } v; v.f = f;
  unsigned u = v.u;
  return (unsigned short)((u + 0x7fffu + ((u >> 16) & 1u)) >> 16);
}

// Load 8 source elements -> 8 bf16 packed in a uint4 (for LDS staging).
__device__ inline uint4 ld8(const float* p) {
  const float4 a = *(const float4*)p;
  const float4 b = *(const float4*)(p + 4);
  union { unsigned short s[8]; uint4 v; } r;
  r.s[0] = f32_to_bf16(a.x); r.s[1] = f32_to_bf16(a.y);
  r.s[2] = f32_to_bf16(a.z); r.s[3] = f32_to_bf16(a.w);
  r.s[4] = f32_to_bf16(b.x); r.s[5] = f32_to_bf16(b.y);
  r.s[6] = f32_to_bf16(b.z); r.s[7] = f32_to_bf16(b.w);
  return r.v;
}
__device__ inline uint4 ld8(const unsigned short* p) { return *(const uint4*)p; }

// C[m,n] = sum_k A[m,k] * B[n,k] (+ bias[n]); bf16 MFMA, fp32 accum.
// A: fp32 or bf16 (TA), B: fp32, C: fp32 or bf16 (TOUT). M%128==0, N%128==0, K%32==0.
template<typename TA, typename TOUT, bool HAS_BIAS>
__global__ __launch_bounds__(256)
void gemm_bt(const TA* __restrict__ A,
             const float* __restrict__ Bm,
             const float* __restrict__ bias,
             TOUT* __restrict__ C,
             int M, int N, int K) {
  __shared__ alignas(16) unsigned short As[128 * 40];
  __shared__ alignas(16) unsigned short Bs[128 * 40];
  const int tid = threadIdx.x;
  const int lane = tid & 63;
  const int wave = tid >> 6;
  const int wr = (wave >> 1) * 64;   // wave row offset in 128-tile
  const int wc = (wave & 1) * 64;    // wave col offset
  const int l15 = lane & 15, quad = lane >> 4;
  const int m0 = blockIdx.x * 128;
  const int n0 = blockIdx.y * 128;

  f32x4 acc[4][4] = {};

  const int nK = K >> 5;
  for (int kt = 0; kt < nK; ++kt) {
    const int k0 = kt << 5;
    __syncthreads();
#pragma unroll
    for (int i = 0; i < 2; ++i) {
      int c = tid + 256 * i;          // 512 chunks of 8 elements per matrix
      int row = c >> 2, kc = c & 3;
      *(uint4*)(As + row * 40 + kc * 8) =
          ld8(A + (size_t)(m0 + row) * K + k0 + kc * 8);
      *(uint4*)(Bs + row * 40 + kc * 8) =
          ld8(Bm + (size_t)(n0 + row) * K + k0 + kc * 8);
    }
    __syncthreads();
    bf16x8 af[4], bfr[4];
#pragma unroll
    for (int i = 0; i < 4; ++i)
      af[i] = *(const bf16x8*)(As + (wr + i * 16 + l15) * 40 + quad * 8);
#pragma unroll
    for (int j = 0; j < 4; ++j)
      bfr[j] = *(const bf16x8*)(Bs + (wc + j * 16 + l15) * 40 + quad * 8);
#pragma unroll
    for (int i = 0; i < 4; ++i)
#pragma unroll
      for (int j = 0; j < 4; ++j)
        acc[i][j] = __builtin_amdgcn_mfma_f32_16x16x32_bf16(af[i], bfr[j], acc[i][j], 0, 0, 0);
  }

#pragma unroll
  for (int j = 0; j < 4; ++j) {
    int n = n0 + wc + j * 16 + l15;
    float bv = 0.f;
    if (HAS_BIAS) bv = bias[n];
#pragma unroll
    for (int i = 0; i < 4; ++i) {
      int mb = m0 + wr + i * 16 + quad * 4;   // C/D layout: row = quad*4+reg, col = l15
#pragma unroll
      for (int r = 0; r < 4; ++r) {
        float v = acc[i][j][r] + bv;
        if constexpr (sizeof(TOUT) == 2)
          C[(size_t)(mb + r) * N + n] = f32_to_bf16(v);
        else
          C[(size_t)(mb + r) * N + n] = v;
      }
    }
  }
}

// Flash attention: grid (LQ/64, NH, BSZ), block 256 (4 waves, 16 q-rows each).
// qp/kp/vp/ctx: [BSZ*L, DIMQ] bf16, head h = cols h*HD .. h*HD+255.
__global__ __launch_bounds__(256)
void attn(const unsigned short* __restrict__ qp,
          const unsigned short* __restrict__ kp,
          const unsigned short* __restrict__ vp,
          unsigned short* __restrict__ ctx) {
  __shared__ alignas(16) unsigned short Ks[32 * 264];   // [kv][d], pad 8
  __shared__ alignas(16) unsigned short Vt[256 * 40];   // [d][kv], pad 8
  __shared__ alignas(16) unsigned short Ps[4][16 * 40]; // per-wave P [16 q][32 kv]
  const int tid = threadIdx.x, lane = tid & 63, wave = tid >> 6;
  const int l15 = lane & 15, quad = lane >> 4;
  const int b = blockIdx.z, h = blockIdx.y;
  const int q0 = blockIdx.x * 64;
  const size_t base = (size_t)b * LQ * DIMQ + h * HD;

  // Preload Q fragments: A-layout A[m=l15][k=quad*8+j], k over 8 steps of 32
  bf16x8 qf[8];
  const unsigned short* qrow = qp + base + (size_t)(q0 + wave * 16 + l15) * DIMQ;
#pragma unroll
  for (int s = 0; s < 8; ++s)
    qf[s] = *(const bf16x8*)(qrow + s * 32 + quad * 8);

  f32x4 oacc[16] = {};                       // O[16 q][256 d]: col=t*16+l15, row=quad*4+r
  float mrow[4] = {-1e30f, -1e30f, -1e30f, -1e30f};
  float lrow[4] = {0.f, 0.f, 0.f, 0.f};

  const unsigned short* kb = kp + base;
  const unsigned short* vb = vp + base;

  for (int kv0 = 0; kv0 < LKV; kv0 += 32) {
    __syncthreads();
#pragma unroll
    for (int i = 0; i < 4; ++i) {
      int c = tid + 256 * i;
      {  // K tile: coalesced copy [32][256] -> Ks
        int row = c >> 5, dc = c & 31;
        *(uint4*)(Ks + row * 264 + dc * 8) =
            *(const uint4*)(kb + (size_t)(kv0 + row) * DIMQ + dc * 8);
      }
      {  // V tile: transposed store -> Vt[d][kv]
        int kvr = c & 31, dc = c >> 5;
        uint4 vv = *(const uint4*)(vb + (size_t)(kv0 + kvr) * DIMQ + dc * 8);
        const unsigned short* vs = (const unsigned short*)&vv;
#pragma unroll
        for (int j = 0; j < 8; ++j)
          Vt[(dc * 8 + j) * 40 + kvr] = vs[j];
      }
    }
    __syncthreads();

    // S = Q K^T for 32 kv cols (2 n-tiles of 16)
    f32x4 sacc0 = {}, sacc1 = {};
#pragma unroll
    for (int s = 0; s < 8; ++s) {
      bf16x8 k0f = *(const bf16x8*)(Ks + l15 * 264 + s * 32 + quad * 8);
      bf16x8 k1f = *(const bf16x8*)(Ks + (16 + l15) * 264 + s * 32 + quad * 8);
      sacc0 = __builtin_amdgcn_mfma_f32_16x16x32_bf16(qf[s], k0f, sacc0, 0, 0, 0);
      sacc1 = __builtin_amdgcn_mfma_f32_16x16x32_bf16(qf[s], k1f, sacc1, 0, 0, 0);
    }

    // Online softmax: row r = quad*4 + i lives on the 16 lanes of this quad
    float alpha[4];
#pragma unroll
    for (int i = 0; i < 4; ++i) {
      float s0 = sacc0[i] * 0.0625f;   // scale = 1/sqrt(256)
      float s1 = sacc1[i] * 0.0625f;
      float mx = fmaxf(s0, s1);
      mx = fmaxf(mx, __shfl_xor(mx, 1));
      mx = fmaxf(mx, __shfl_xor(mx, 2));
      mx = fmaxf(mx, __shfl_xor(mx, 4));
      mx = fmaxf(mx, __shfl_xor(mx, 8));
      float mn = fmaxf(mrow[i], mx);
      float p0 = __expf(s0 - mn);
      float p1 = __expf(s1 - mn);
      Ps[wave][(quad * 4 + i) * 40 + l15] = f32_to_bf16(p0);
      Ps[wave][(quad * 4 + i) * 40 + 16 + l15] = f32_to_bf16(p1);
      float rs = p0 + p1;
      rs += __shfl_xor(rs, 1);
      rs += __shfl_xor(rs, 2);
      rs += __shfl_xor(rs, 4);
      rs += __shfl_xor(rs, 8);
      float a = __expf(mrow[i] - mn);
      lrow[i] = lrow[i] * a + rs;
      mrow[i] = mn;
      alpha[i] = a;
    }
    __syncthreads();  // make cross-lane Ps writes visible before A-frag read

    // P in A-layout: P[m=l15][k=quad*8+j], one K=32 step
    bf16x8 pf = *(const bf16x8*)(Ps[wave] + l15 * 40 + quad * 8);
#pragma unroll
    for (int t = 0; t < 16; ++t)
#pragma unroll
      for (int r = 0; r < 4; ++r) oacc[t][r] *= alpha[r];
#pragma unroll
    for (int t = 0; t < 16; ++t) {
      bf16x8 vf = *(const bf16x8*)(Vt + (t * 16 + l15) * 40 + quad * 8);
      oacc[t] = __builtin_amdgcn_mfma_f32_16x16x32_bf16(pf, vf, oacc[t], 0, 0, 0);
    }
  }

  float inv[4];
#pragma unroll
  for (int r = 0; r < 4; ++r) inv[r] = 1.0f / lrow[r];
  unsigned short* cb = ctx + base;
#pragma unroll
  for (int t = 0; t < 16; ++t) {
    int col = t * 16 + l15;
#pragma unroll
    for (int r = 0; r < 4; ++r) {
      int row = q0 + wave * 16 + quad * 4 + r;
      cb[(size_t)row * DIMQ + col] = f32_to_bf16(oacc[t][r] * inv[r]);
    }
  }
}

extern "C" void kernel_launch(void* const* d_in, const int* in_sizes, int n_in,
                              void* d_out, int out_size, void* d_ws, size_t ws_size,
                              hipStream_t stream) {
  const float* q  = (const float*)d_in[0];
  const float* kv = (const float*)d_in[1];
  const float* Wq = (const float*)d_in[2];
  const float* Wk = (const float*)d_in[3];
  const float* Wv = (const float*)d_in[4];
  const float* Wo = (const float*)d_in[5];
  const float* bo = (const float*)d_in[6];
  float* out = (float*)d_out;

  const size_t NE = (size_t)BSZ * LQ * DIMQ;   // 8388608 elems per intermediate
  // bf16 intermediates: qp parked in d_out's first 16 MB (dead before final
  // GEMM overwrites d_out); kp/vp/ctx in ws (48 MB total).
  unsigned short* qp  = (unsigned short*)d_out;
  unsigned short* kp  = (unsigned short*)d_ws;
  unsigned short* vp  = kp + NE;
  unsigned short* ctx = vp + NE;

  dim3 blk(256);
  const int M = BSZ * LQ;  // 8192
  gemm_bt<float, unsigned short, false>
      <<<dim3(M / 128, DIMQ / 128), blk, 0, stream>>>(q,  Wq, nullptr, qp, M, DIMQ, 1024);
  gemm_bt<float, unsigned short, false>
      <<<dim3(M / 128, DIMQ / 128), blk, 0, stream>>>(kv, Wk, nullptr, kp, M, DIMQ, 768);
  gemm_bt<float, unsigned short, false>
      <<<dim3(M / 128, DIMQ / 128), blk, 0, stream>>>(kv, Wv, nullptr, vp, M, DIMQ, 768);
  attn<<<dim3(LQ / 64, NH, BSZ), blk, 0, stream>>>(qp, kp, vp, ctx);
  gemm_bt<unsigned short, float, true>
      <<<dim3(M / 128, DIMQ / 128), blk, 0, stream>>>(ctx, Wo, bo, out, M, DIMQ, 1024);
}

// Round 3
// 380.739 us; speedup vs baseline: 1.2050x; 1.2050x over previous
//
#include <hip/hip_runtime.h>

#define DIMQ 1024
#define NH 4
#define HD 256
#define BSZ 4
#define LQ 2048
#define LKV 2048

typedef __attribute__((ext_vector_type(8))) short bf16x8;
typedef __attribute__((ext_vector_type(4))) float f32x4;
typedef unsigned short ushort_t;

__device__ inline unsigned short f32_to_bf16(float f) {
  union { float f; unsigned u; } v; v.f = f;
  unsigned u = v.u;
  return (unsigned short)((u + 0x7fffu + ((u >> 16) & 1u)) >> 16);
}

__device__ inline uint4 ld8cvt(const float* p) {
  const float4 a = *(const float4*)p;
  const float4 b = *(const float4*)(p + 4);
  union { unsigned short s[8]; uint4 v; } r;
  r.s[0] = f32_to_bf16(a.x); r.s[1] = f32_to_bf16(a.y);
  r.s[2] = f32_to_bf16(a.z); r.s[3] = f32_to_bf16(a.w);
  r.s[4] = f32_to_bf16(b.x); r.s[5] = f32_to_bf16(b.y);
  r.s[6] = f32_to_bf16(b.z); r.s[7] = f32_to_bf16(b.w);
  return r.v;
}

// async global->LDS, 16 B per lane; lds dest must be wave-uniform base.
__device__ __forceinline__ void gl2lds16(const void* gptr, void* lptr) {
  __builtin_amdgcn_global_load_lds(
      (const __attribute__((address_space(1))) void*)gptr,
      (__attribute__((address_space(3))) void*)lptr, 16, 0, 0);
}

// fp32 -> bf16 conversion, up to 5 segments (grid.y = segment id).
__global__ __launch_bounds__(256)
void cvt5(const float* s0, const float* s1, const float* s2, const float* s3,
          const float* s4, unsigned short* d0, unsigned short* d1,
          unsigned short* d2, unsigned short* d3, unsigned short* d4,
          long n0, long n1, long n2, long n3, long n4) {
  const float* s; unsigned short* d; long n;
  switch (blockIdx.y) {
    case 0: s = s0; d = d0; n = n0; break;
    case 1: s = s1; d = d1; n = n1; break;
    case 2: s = s2; d = d2; n = n2; break;
    case 3: s = s3; d = d3; n = n3; break;
    default: s = s4; d = d4; n = n4; break;
  }
  long i = ((long)blockIdx.x * 256 + threadIdx.x) * 8;
  if (i < n) *(uint4*)(d + i) = ld8cvt(s + i);
}

// vp [BSZ*LKV][DIMQ] -> vpT [BSZ][DIMQ][LKV], bf16.
__global__ __launch_bounds__(256)
void transpose_k(const unsigned short* __restrict__ vp,
                 unsigned short* __restrict__ vpT) {
  __shared__ unsigned short T[64][72];
  const int l0g = blockIdx.x * 64;         // global row in vp
  const int b = l0g / LKV, l0 = l0g % LKV;
  const int n0 = blockIdx.y * 64;
  const int tid = threadIdx.x;
  const int r = tid >> 3, c = tid & 7;     // r 0..31, c 0..7
#pragma unroll
  for (int p = 0; p < 2; ++p) {
    int row = p * 32 + r;
    *(uint4*)&T[row][c * 8] = *(const uint4*)(vp + (size_t)(l0g + row) * DIMQ + n0 + c * 8);
  }
  __syncthreads();
#pragma unroll
  for (int p = 0; p < 2; ++p) {
    int n = p * 32 + r;
    union { unsigned short s[8]; uint4 v; } t;
#pragma unroll
    for (int j = 0; j < 8; ++j) t.s[j] = T[c * 8 + j][n];
    *(uint4*)(vpT + ((size_t)b * DIMQ + n0 + n) * LKV + l0 + c * 8) = t.v;
  }
}

// C[m,n] = sum_k A[m,k]*B[n,k] (+bias); bf16 in, fp32 acc. m97-style staging.
template<typename TOUT, bool HAS_BIAS>
__global__ __launch_bounds__(256)
void gemm_bt(const unsigned short* __restrict__ A,
             const unsigned short* __restrict__ Bm,
             const float* __restrict__ bias,
             TOUT* __restrict__ C,
             int M, int N, int K) {
  __shared__ alignas(16) unsigned short As[128 * 32];
  __shared__ alignas(16) unsigned short Bs[128 * 32];
  const int tid = threadIdx.x;
  const int lane = tid & 63;
  const int wave = tid >> 6;
  const int wr = (wave >> 1) * 64, wc = (wave & 1) * 64;
  const int l15 = lane & 15, quad = lane >> 4;
  const int lr = lane >> 2, lc = lane & 3;       // staging: 16 rows x 64 B per wave-chunk
  const int m0 = blockIdx.x * 128;
  const int n0 = blockIdx.y * 128;

  f32x4 acc[4][4] = {};
  const int nK = K >> 5;
  for (int kt = 0; kt < nK; ++kt) {
    const int k0 = kt << 5;
    __syncthreads();
#pragma unroll
    for (int i = 0; i < 2; ++i) {
      int c = wave * 2 + i;                       // 8 chunks of 16 rows
      gl2lds16(A + (size_t)(m0 + c * 16 + lr) * K + k0 + lc * 8, As + c * 512);
      gl2lds16(Bm + (size_t)(n0 + c * 16 + lr) * K + k0 + lc * 8, Bs + c * 512);
    }
    __syncthreads();                              // drains vmcnt before reads
    bf16x8 af[4], bfr[4];
#pragma unroll
    for (int i = 0; i < 4; ++i)
      af[i] = *(const bf16x8*)(As + (wr + i * 16 + l15) * 32 + quad * 8);
#pragma unroll
    for (int j = 0; j < 4; ++j)
      bfr[j] = *(const bf16x8*)(Bs + (wc + j * 16 + l15) * 32 + quad * 8);
#pragma unroll
    for (int i = 0; i < 4; ++i)
#pragma unroll
      for (int j = 0; j < 4; ++j)
        acc[i][j] = __builtin_amdgcn_mfma_f32_16x16x32_bf16(af[i], bfr[j], acc[i][j], 0, 0, 0);
  }

#pragma unroll
  for (int j = 0; j < 4; ++j) {
    int n = n0 + wc + j * 16 + l15;
    float bv = 0.f;
    if (HAS_BIAS) bv = bias[n];
#pragma unroll
    for (int i = 0; i < 4; ++i) {
      int mb = m0 + wr + i * 16 + quad * 4;       // C/D: row=quad*4+reg, col=l15
#pragma unroll
      for (int r = 0; r < 4; ++r) {
        float v = acc[i][j][r] + bv;
        if constexpr (sizeof(TOUT) == 2)
          C[(size_t)(mb + r) * N + n] = f32_to_bf16(v);
        else
          C[(size_t)(mb + r) * N + n] = v;
      }
    }
  }
}

// Flash attention, KV tile 64, async staging, pre-transposed V.
// qp,kp: [BSZ*LQ][DIMQ] bf16; vpT: [BSZ][DIMQ][LKV] bf16; ctx: [BSZ*LQ][DIMQ].
__global__ __launch_bounds__(256)
void attn(const unsigned short* __restrict__ qp,
          const unsigned short* __restrict__ kp,
          const unsigned short* __restrict__ vpT,
          unsigned short* __restrict__ ctx) {
  __shared__ alignas(16) unsigned short Ks[8 * 64 * 32];   // [s][kv 64][k 32]
  __shared__ alignas(16) unsigned short Vt[2 * 256 * 32];  // [u][d 256][kv 32]
  __shared__ alignas(16) unsigned short Ps[4][16 * 72];    // per-wave P [16 q][64 kv] pad8
  const int tid = threadIdx.x, lane = tid & 63, wave = tid >> 6;
  const int l15 = lane & 15, quad = lane >> 4;
  const int lr = lane >> 2, lc = lane & 3;
  const int b = blockIdx.z, h = blockIdx.y;
  const int q0 = blockIdx.x * 64;
  const size_t base = (size_t)b * LQ * DIMQ + h * HD;

  bf16x8 qf[8];
  const unsigned short* qrow = qp + base + (size_t)(q0 + wave * 16 + l15) * DIMQ;
#pragma unroll
  for (int s = 0; s < 8; ++s)
    qf[s] = *(const bf16x8*)(qrow + s * 32 + quad * 8);

  f32x4 oacc[16] = {};
  float mrow[4] = {-1e30f, -1e30f, -1e30f, -1e30f};
  float lrow[4] = {0.f, 0.f, 0.f, 0.f};

  const unsigned short* kb = kp + base;
  const unsigned short* vtb = vpT + ((size_t)b * DIMQ + h * HD) * LKV;

  for (int kv0 = 0; kv0 < LKV; kv0 += 64) {
    __syncthreads();
#pragma unroll
    for (int i = 0; i < 8; ++i) {            // K: 32 chunks of 1 KB
      int c = i * 4 + wave, s = c & 7, g = c >> 3;
      gl2lds16(kb + (size_t)(kv0 + g * 16 + lr) * DIMQ + s * 32 + lc * 8,
               Ks + s * 2048 + g * 512);
    }
#pragma unroll
    for (int i = 0; i < 8; ++i) {            // V^T: 32 chunks of 1 KB
      int c = i * 4 + wave, u = c >> 4, g = c & 15;
      gl2lds16(vtb + (size_t)(g * 16 + lr) * LKV + kv0 + u * 32 + lc * 8,
               Vt + u * 8192 + g * 512);
    }
    __syncthreads();

    f32x4 sacc[4] = {};
#pragma unroll
    for (int s = 0; s < 8; ++s)
#pragma unroll
      for (int j = 0; j < 4; ++j) {
        bf16x8 kf = *(const bf16x8*)(Ks + s * 2048 + (j * 16 + l15) * 32 + quad * 8);
        sacc[j] = __builtin_amdgcn_mfma_f32_16x16x32_bf16(qf[s], kf, sacc[j], 0, 0, 0);
      }

    float alpha[4];
#pragma unroll
    for (int i = 0; i < 4; ++i) {
      float sv[4];
#pragma unroll
      for (int j = 0; j < 4; ++j) sv[j] = sacc[j][i] * 0.0625f;
      float mx = fmaxf(fmaxf(sv[0], sv[1]), fmaxf(sv[2], sv[3]));
      mx = fmaxf(mx, __shfl_xor(mx, 1));
      mx = fmaxf(mx, __shfl_xor(mx, 2));
      mx = fmaxf(mx, __shfl_xor(mx, 4));
      mx = fmaxf(mx, __shfl_xor(mx, 8));
      float mn = fmaxf(mrow[i], mx);
      float rs = 0.f;
#pragma unroll
      for (int j = 0; j < 4; ++j) {
        float p = __expf(sv[j] - mn);
        rs += p;
        Ps[wave][(quad * 4 + i) * 72 + j * 16 + l15] = f32_to_bf16(p);
      }
      rs += __shfl_xor(rs, 1);
      rs += __shfl_xor(rs, 2);
      rs += __shfl_xor(rs, 4);
      rs += __shfl_xor(rs, 8);
      float a = __expf(mrow[i] - mn);
      lrow[i] = lrow[i] * a + rs;
      mrow[i] = mn;
      alpha[i] = a;
    }

#pragma unroll
    for (int t = 0; t < 16; ++t)
#pragma unroll
      for (int r = 0; r < 4; ++r) oacc[t][r] *= alpha[r];

#pragma unroll
    for (int u = 0; u < 2; ++u) {
      bf16x8 pf = *(const bf16x8*)(Ps[wave] + l15 * 72 + u * 32 + quad * 8);
#pragma unroll
      for (int t = 0; t < 16; ++t) {
        bf16x8 vf = *(const bf16x8*)(Vt + u * 8192 + (t * 16 + l15) * 32 + quad * 8);
        oacc[t] = __builtin_amdgcn_mfma_f32_16x16x32_bf16(pf, vf, oacc[t], 0, 0, 0);
      }
    }
  }

  float inv[4];
#pragma unroll
  for (int r = 0; r < 4; ++r) inv[r] = 1.0f / lrow[r];
  unsigned short* cb = ctx + base;
#pragma unroll
  for (int t = 0; t < 16; ++t) {
    int col = t * 16 + l15;
#pragma unroll
    for (int r = 0; r < 4; ++r) {
      int row = q0 + wave * 16 + quad * 4 + r;
      cb[(size_t)row * DIMQ + col] = f32_to_bf16(oacc[t][r] * inv[r]);
    }
  }
}

extern "C" void kernel_launch(void* const* d_in, const int* in_sizes, int n_in,
                              void* d_out, int out_size, void* d_ws, size_t ws_size,
                              hipStream_t stream) {
  const float* q  = (const float*)d_in[0];
  const float* kv = (const float*)d_in[1];
  const float* Wq = (const float*)d_in[2];
  const float* Wk = (const float*)d_in[3];
  const float* Wv = (const float*)d_in[4];
  const float* Wo = (const float*)d_in[5];
  const float* bo = (const float*)d_in[6];
  float* out = (float*)d_out;

  const long NQ = (long)BSZ * LQ * DIMQ;       // 8388608
  const long NKV = (long)BSZ * LKV * 768;      // 6291456
  const long NWQ = (long)DIMQ * DIMQ;          // 1048576
  const long NWK = (long)DIMQ * 768;           // 786432

  // d_out parking (both dead before final GEMM writes d_out):
  unsigned short* qp = (unsigned short*)d_out;             // [0, NQ)
  unsigned short* kp = qp + NQ;                            // [NQ, 2NQ)
  // ws layout (36.7 MB):
  unsigned short* kv_bf = (unsigned short*)d_ws;           // NKV
  unsigned short* Wq_bf = kv_bf + NKV;                     // NWQ
  unsigned short* Wk_bf = Wq_bf + NWQ;                     // NWK
  unsigned short* Wv_bf = Wk_bf + NWK;                     // NWK
  unsigned short* Wo_bf = Wv_bf + NWK;                     // NWQ
  unsigned short* BUF1  = Wo_bf + NWQ;                     // NQ: vp -> q_bf -> ctx
  unsigned short* vpT   = BUF1 + NQ;                       // NQ

  dim3 blk(256);
  const int M = BSZ * LQ;  // 8192

  // 1) convert kv + all weights to bf16
  cvt5<<<dim3(3072, 5), blk, 0, stream>>>(kv, Wq, Wk, Wv, Wo,
                                          kv_bf, Wq_bf, Wk_bf, Wv_bf, Wo_bf,
                                          NKV, NWQ, NWK, NWK, NWQ);
  // 2) kp = kv_bf Wk^T ; vp = kv_bf Wv^T
  gemm_bt<unsigned short, false><<<dim3(M/128, DIMQ/128), blk, 0, stream>>>(kv_bf, Wk_bf, nullptr, kp,   M, DIMQ, 768);
  gemm_bt<unsigned short, false><<<dim3(M/128, DIMQ/128), blk, 0, stream>>>(kv_bf, Wv_bf, nullptr, BUF1, M, DIMQ, 768);
  // 3) vpT = transpose(vp)
  transpose_k<<<dim3(M/64, DIMQ/64), blk, 0, stream>>>(BUF1, vpT);
  // 4) q -> bf16 (into BUF1, vp now dead)
  cvt5<<<dim3(4096, 1), blk, 0, stream>>>(q, nullptr, nullptr, nullptr, nullptr,
                                          BUF1, nullptr, nullptr, nullptr, nullptr,
                                          NQ, 0, 0, 0, 0);
  // 5) qp = q_bf Wq^T
  gemm_bt<unsigned short, false><<<dim3(M/128, DIMQ/128), blk, 0, stream>>>(BUF1, Wq_bf, nullptr, qp, M, DIMQ, 1024);
  // 6) attention -> ctx (BUF1, q_bf dead)
  attn<<<dim3(LQ/64, NH, BSZ), blk, 0, stream>>>(qp, kp, vpT, BUF1);
  // 7) out = ctx Wo^T + bo (fp32)
  gemm_bt<float, true><<<dim3(M/128, DIMQ/128), blk, 0, stream>>>(BUF1, Wo_bf, bo, out, M, DIMQ, 1024);
}